// Round 11
// baseline (2136.902 us; speedup 1.0000x reference)
//
#include <hip/hip_runtime.h>
#include <hip/hip_bf16.h>
#include <math.h>

// Problem constants
// B=32 S=256 E=300 H=256(4H=1024) L=4000 D=256 G=512 V=50000 LIN1=512 LIN2=256, 2H=512

typedef __attribute__((ext_vector_type(8))) short bfrag;   // 8 bf16 (4 VGPRs)
typedef __attribute__((ext_vector_type(4))) float ffrag;   // 4 fp32 acc

__device__ __forceinline__ ushort f2bf(float x) {
    union { float f; unsigned u; } c; c.f = x;
    const unsigned r = c.u + 0x7fffu + ((c.u >> 16) & 1u);
    return (ushort)(r >> 16);
}
__device__ __forceinline__ float bf2f(ushort h) {
    union { unsigned u; float f; } c; c.u = (unsigned)h << 16;
    return c.f;
}

// ---------------------------------------------------------------------------
// Split-bf16 MFMA GEMM: C = A * B^T via 3-term split (hh + hl + lh).
// A: [M][lda] bf16, row = [hi(0..K) | lo(0..K)]; B likewise. Tile 128x128,
// BK=32, 4 waves (2x2 of 64x64). LDS rows padded to 40 bf16 (80B stride).
// Pipeline: next-tile loads issued before the MFMA phase (latency hides).
// [R10 lesson: global_load_lds + linear [128][32] LDS regressed — 64B row
// stride gives parity-only bank spread (8-way windows) and the vmcnt(0)
// drain loses the reg-staged pipeline's latency hiding. This reg-staged
// version is the measured best.]
// ---------------------------------------------------------------------------
template<bool BIAS, bool ADDROW, bool RELU, bool OUTF, bool OUTS>
__global__ __launch_bounds__(256) void mgemm_k(
    const ushort* __restrict__ A, const ushort* __restrict__ B,
    float* __restrict__ Cf, ushort* __restrict__ Cs,
    int M, int N, int K, int lda, int ldb, int ldc, int ldcs,
    long abs_, long bbs_, long cbs_, long csbs_,
    const float* __restrict__ bias,
    const float* __restrict__ addrow, int addmod, int ldadd)
{
    const int tid = threadIdx.x;
    const int ln = tid & 63;
    const int wv = tid >> 6;
    const int wm = wv >> 1, wn = wv & 1;
    const int m0 = blockIdx.x * 128, n0 = blockIdx.y * 128;
    const int z = blockIdx.z;
    A += (size_t)z * abs_;
    B += (size_t)z * bbs_;

    __shared__ ushort Ah[128 * 40], Al[128 * 40], Bh[128 * 40], Bl[128 * 40];

    ffrag acc[4][4];
#pragma unroll
    for (int i = 0; i < 4; ++i)
#pragma unroll
        for (int j = 0; j < 4; ++j) acc[i][j] = ffrag{0.f, 0.f, 0.f, 0.f};

    const int sr = tid >> 1;
    const int sk = (tid & 1) * 16;
    const int am = min(m0 + sr, M - 1);
    const int bn = n0 + sr;
    const int fr = ln & 15;
    const int fk = (ln >> 4) * 8;

    const ushort* arow = A + (size_t)am * lda + sk;
    const ushort* brow = B + (size_t)bn * ldb + sk;

    bfrag ah0, ah1, al0, al1, bh0, bh1, bl0, bl1;
    {
        const ushort* ap = arow;
        const ushort* bp = brow;
        ah0 = *(const bfrag*)ap;       ah1 = *(const bfrag*)(ap + 8);
        al0 = *(const bfrag*)(ap + K); al1 = *(const bfrag*)(ap + K + 8);
        bh0 = *(const bfrag*)bp;       bh1 = *(const bfrag*)(bp + 8);
        bl0 = *(const bfrag*)(bp + K); bl1 = *(const bfrag*)(bp + K + 8);
    }

    for (int k0 = 0; k0 < K; k0 += 32) {
        __syncthreads();   // previous iteration's frag reads complete
        *(bfrag*)&Ah[sr * 40 + sk] = ah0;  *(bfrag*)&Ah[sr * 40 + sk + 8] = ah1;
        *(bfrag*)&Al[sr * 40 + sk] = al0;  *(bfrag*)&Al[sr * 40 + sk + 8] = al1;
        *(bfrag*)&Bh[sr * 40 + sk] = bh0;  *(bfrag*)&Bh[sr * 40 + sk + 8] = bh1;
        *(bfrag*)&Bl[sr * 40 + sk] = bl0;  *(bfrag*)&Bl[sr * 40 + sk + 8] = bl1;
        __syncthreads();   // tile staged
        if (k0 + 32 < K) {  // issue next-tile loads early
            const ushort* ap = arow + k0 + 32;
            const ushort* bp = brow + k0 + 32;
            ah0 = *(const bfrag*)ap;       ah1 = *(const bfrag*)(ap + 8);
            al0 = *(const bfrag*)(ap + K); al1 = *(const bfrag*)(ap + K + 8);
            bh0 = *(const bfrag*)bp;       bh1 = *(const bfrag*)(bp + 8);
            bl0 = *(const bfrag*)(bp + K); bl1 = *(const bfrag*)(bp + K + 8);
        }
        bfrag afh[4], afl[4];
#pragma unroll
        for (int i = 0; i < 4; ++i) {
            const int ar = (wm * 64 + i * 16 + fr) * 40 + fk;
            afh[i] = *(const bfrag*)&Ah[ar];
            afl[i] = *(const bfrag*)&Al[ar];
        }
#pragma unroll
        for (int j = 0; j < 4; ++j) {
            const int br = (wn * 64 + j * 16 + fr) * 40 + fk;
            const bfrag bfh = *(const bfrag*)&Bh[br];
            const bfrag bfl = *(const bfrag*)&Bl[br];
#pragma unroll
            for (int i = 0; i < 4; ++i) {
                acc[i][j] = __builtin_amdgcn_mfma_f32_16x16x32_bf16(afh[i], bfh, acc[i][j], 0, 0, 0);
                acc[i][j] = __builtin_amdgcn_mfma_f32_16x16x32_bf16(afh[i], bfl, acc[i][j], 0, 0, 0);
                acc[i][j] = __builtin_amdgcn_mfma_f32_16x16x32_bf16(afl[i], bfh, acc[i][j], 0, 0, 0);
            }
        }
    }

#pragma unroll
    for (int i = 0; i < 4; ++i) {
#pragma unroll
        for (int rg = 0; rg < 4; ++rg) {
            const int gm = m0 + wm * 64 + i * 16 + (ln >> 4) * 4 + rg;
            if (gm >= M) continue;
            const float* addp = ADDROW ? (addrow + (size_t)(gm % addmod) * ldadd) : nullptr;
#pragma unroll
            for (int j = 0; j < 4; ++j) {
                const int gn = n0 + wn * 64 + j * 16 + fr;
                float v = acc[i][j][rg];
                if (BIAS) v += bias[gn];
                if (ADDROW) v += addp[gn];
                if (RELU) v = fmaxf(v, 0.f);
                if (OUTF) Cf[(size_t)z * cbs_ + (size_t)gm * ldc + gn] = v;
                if (OUTS) {
                    const ushort h = f2bf(v);
                    const ushort l = f2bf(v - bf2f(h));
                    ushort* cp = Cs + (size_t)z * csbs_ + (size_t)gm * ldcs;
                    cp[gn] = h;
                    cp[N + gn] = l;
                }
            }
        }
    }
}

// ---------------------------------------------------------------------------
// Gather(optional) + split + zero-pad: row r of src (K cols) -> [r][2*Kpad]
// ---------------------------------------------------------------------------
__global__ void gsplit_k(const float* __restrict__ src, const int* __restrict__ tok,
                         ushort* __restrict__ outp, int K, int Kpad)
{
    const int r = blockIdx.x;
    const float* s = src + (size_t)(tok ? tok[r] : r) * K;
    ushort* o = outp + (size_t)r * 2 * Kpad;
    for (int k = threadIdx.x; k < Kpad; k += blockDim.x) {
        const float x = (k < K) ? s[k] : 0.f;
        const ushort h = f2bf(x);
        const ushort l = f2bf(x - bf2f(h));
        o[k] = h;
        o[Kpad + k] = l;
    }
}

// ---------------------------------------------------------------------------
// fp32 [rows][K] -> split bf16 [rows][2K] (hi | lo)
// ---------------------------------------------------------------------------
__global__ void split_k(const float* __restrict__ in, ushort* __restrict__ outp,
                        int rows, int K)
{
    const int i = blockIdx.x * 256 + threadIdx.x;
    if (i >= rows * K) return;
    const int r = i / K, k = i - r * K;
    const float x = in[i];
    const ushort h = f2bf(x);
    const ushort l = f2bf(x - bf2f(h));
    ushort* o = outp + (size_t)r * 2 * K;
    o[k] = h;
    o[K + k] = l;
}

// ---------------------------------------------------------------------------
// fp32 [R][C] -> split-transposed bf16 [C][2R]
// ---------------------------------------------------------------------------
__global__ __launch_bounds__(256) void tsplit_k(
    const float* __restrict__ in, ushort* __restrict__ outp,
    int R, int C, int ldin, long ibs, long obs)
{
    __shared__ float t[64][65];
    const int c0 = blockIdx.x * 64, r0 = blockIdx.y * 64;
    in   += (size_t)blockIdx.z * ibs;
    outp += (size_t)blockIdx.z * obs;
    const int tx = threadIdx.x & 15, ty = threadIdx.x >> 4;
#pragma unroll
    for (int i = 0; i < 4; ++i) {
        const int r = ty * 4 + i;
        const float4 v = *(const float4*)&in[(size_t)(r0 + r) * ldin + c0 + tx * 4];
        t[tx * 4 + 0][r] = v.x;
        t[tx * 4 + 1][r] = v.y;
        t[tx * 4 + 2][r] = v.z;
        t[tx * 4 + 3][r] = v.w;
    }
    __syncthreads();
    const int R2 = 2 * R;
#pragma unroll
    for (int i = 0; i < 4; ++i) {
        const int c = ty * 4 + i;
        ushort h[4], l[4];
#pragma unroll
        for (int k2 = 0; k2 < 4; ++k2) {
            const float x = t[c][tx * 4 + k2];
            h[k2] = f2bf(x);
            l[k2] = f2bf(x - bf2f(h[k2]));
        }
        uint2 hw, lw;
        hw.x = (unsigned)h[0] | ((unsigned)h[1] << 16);
        hw.y = (unsigned)h[2] | ((unsigned)h[3] << 16);
        lw.x = (unsigned)l[0] | ((unsigned)l[1] << 16);
        lw.y = (unsigned)l[2] | ((unsigned)l[3] << 16);
        *(uint2*)&outp[(size_t)(c0 + c) * R2 + r0 + tx * 4] = hw;
        *(uint2*)&outp[(size_t)(c0 + c) * R2 + R + r0 + tx * 4] = lw;
    }
}

// ---------------------------------------------------------------------------
// Register-resident biLSTM scan v7: R7 stamp protocol refined to PER-WAVE
// sub-stamps. Each wave drains its own 4 agent-scope h-stores (wave-local
// s_waitcnt 0 + sched_barrier pin) and publishes stamp[p][q*16+wv]=st+1 —
// B3 deleted (h_lds overwrite stays guarded by next step's B1). Partner
// poll: wave0's 64 lanes load the 64 sub-stamps in one parallel volley,
// uniform __all exit (NOT R8's divergent per-lane spin). rnn store moved
// after the stamp (off the serial chain). 2 barriers/step.
// Co-residency: 256 blocks <= 256 CUs (1 block/CU) => no deadlock.
// ---------------------------------------------------------------------------
__global__ __launch_bounds__(1024) void lstm_reg_k(
    const float* __restrict__ gxf, const float* __restrict__ gxb,
    const float* __restrict__ whf, const float* __restrict__ whb,
    float* __restrict__ rnn, float* hbuf, int* stamp)
{
    const int p = blockIdx.x;          // pair: batch b=p>>1, dir=p&1
    const int q = blockIdx.y;          // quarter (owns units [64q,64q+64))
    const int b = p >> 1, dir = p & 1;
    const float* xg = dir ? gxb : gxf;
    const float* W  = dir ? whb : whf;
    const int tid = threadIdx.x;
    const int wv = tid >> 6, lane = tid & 63;
    const int ul = lane >> 4;           // unit-local 0..3
    const int ks = (lane >> 2) & 3;     // 64-float k-slice
    const int gt = lane & 3;            // gate 0..3 (i,f,g,o)
    const int u  = wv * 4 + ul;         // block unit 0..63
    const int grow = gt * 256 + q * 64 + u;

    float4 w[16];
    {
        const float4* wp = (const float4*)(W + (size_t)grow * 256 + ks * 64);
#pragma unroll
        for (int i = 0; i < 16; ++i) w[i] = wp[i];
    }

    __shared__ float h_lds[4 * 68];
    __shared__ float xg_lds[320];       // [u*5 + gt], stride 5 = conflict-free

    float* hb0 = hbuf + (size_t)p * 256;            // parity 0
    float* hb1 = hbuf + (size_t)(64 + p) * 256;     // parity 1
    int* sp  = stamp + p * 64;          // this pair's 64 sub-stamps (4q x 16w)
    int* spq = sp + q * 16;             // our quarter's 16 wave stamps

    const size_t xgb = (size_t)b * 256;
    const int g2 = (tid >> 6) * 256 + q * 64 + (tid & 63);  // staging map (tid<256)
    float c = 0.f;                                   // redundant in all lanes
    float xg_cur = 0.f;
    if (tid < 256) xg_cur = xg[(xgb + (dir ? 255 : 0)) * 1024 + g2];

    for (int st = 0; st < 256; ++st) {
        const int ts = dir ? 255 - st : st;
        if (st > 0 && tid < 64) {       // wave0: 64-lane parallel stamp volley
            const int* pl = sp + tid;
            while (true) {
                const int s = __hip_atomic_load(pl, __ATOMIC_RELAXED, __HIP_MEMORY_SCOPE_AGENT);
                if (__all(s >= st)) break;
            }
        }
        __syncthreads();   // B1: all partners' h[st-1] published; also guards
                           //     h_lds/xg_lds overwrite vs prev step's readers
        if (tid < 256) {
            float hv = 0.f;
            if (st > 0) {
                const float* src = (st & 1) ? hb0 : hb1;   // parity (st-1)&1
                hv = __hip_atomic_load(&src[tid], __ATOMIC_RELAXED, __HIP_MEMORY_SCOPE_AGENT);
            }
            h_lds[(tid >> 6) * 68 + (tid & 63)] = hv;
            xg_lds[(tid & 63) * 5 + (tid >> 6)] = xg_cur;  // [u][gt] stride-5
        }
        __syncthreads();   // B2: h_lds/xg_lds ready
        float acc = 0.f;
        {
            const float4* hp = (const float4*)&h_lds[ks * 68];
#pragma unroll
            for (int i = 0; i < 16; ++i) {
                const float4 hv = hp[i];
                acc = fmaf(w[i].x, hv.x, acc);
                acc = fmaf(w[i].y, hv.y, acc);
                acc = fmaf(w[i].z, hv.z, acc);
                acc = fmaf(w[i].w, hv.w, acc);
            }
        }
        acc += __shfl_xor(acc, 4);      // reduce over ks (bits 2-3)
        acc += __shfl_xor(acc, 8);
        const float g = acc + xg_lds[u * 5 + gt];
        // gather quartet gates via xor-shfls; all lanes act redundantly
        const float t1 = __shfl_xor(g, 1);
        const float t2 = __shfl_xor(g, 2);
        const float t3 = __shfl_xor(t1, 2);
        const float g0 = (gt == 0) ? g : (gt == 1) ? t1 : (gt == 2) ? t2 : t3;
        const float g1 = (gt == 1) ? g : (gt == 0) ? t1 : (gt == 3) ? t2 : t3;
        const float g2v = (gt == 2) ? g : (gt == 3) ? t1 : (gt == 0) ? t2 : t3;
        const float g3v = (gt == 3) ? g : (gt == 2) ? t1 : (gt == 1) ? t2 : t3;
        const float si = 1.f / (1.f + __expf(-g0));
        const float sf = 1.f / (1.f + __expf(-g1));
        const float so = 1.f / (1.f + __expf(-g3v));
        const float tg = 1.f - 2.f / (__expf(2.f * g2v) + 1.f);
        c = sf * c + si * tg;
        const float tc = 1.f - 2.f / (__expf(2.f * c) + 1.f);
        const float hn = so * tc;
        const bool writer = ((lane & 15) == 0);      // ks==0 && gt==0: 4/wave
        if (writer) {
            float* dst = (st & 1) ? hb1 : hb0;       // parity st&1
            __hip_atomic_store(&dst[q * 64 + u], hn, __ATOMIC_RELAXED, __HIP_MEMORY_SCOPE_AGENT);
        }
        // wave-local drain of this wave's h-stores, then publish sub-stamp
        __builtin_amdgcn_s_waitcnt(0);
        __builtin_amdgcn_sched_barrier(0);
        if (lane == 0) {
            __hip_atomic_store(&spq[wv], st + 1, __ATOMIC_RELAXED, __HIP_MEMORY_SCOPE_AGENT);
        }
        // off-chain: rnn store + next xg prefetch
        if (writer) {
            rnn[(xgb + ts) * 512 + (size_t)dir * 256 + q * 64 + u] = hn;
        }
        if (tid < 256 && st < 255) {
            const int tsn = dir ? 254 - st : st + 1;
            xg_cur = xg[(xgb + tsn) * 1024 + g2];
        }
    }
}

__global__ void init_cnt_k(int* stamp) {
    const int i = blockIdx.x * blockDim.x + threadIdx.x;
    if (i < 4096) stamp[i] = 0;
}

// ---------------------------------------------------------------------------
// Masked softmax over s (256); writes split-bf16 probs in place.
// ---------------------------------------------------------------------------
__global__ __launch_bounds__(256) void softmax_split_k(
    float* __restrict__ sc, const int* __restrict__ tokens, int b0)
{
    const int bb = blockIdx.y;
    const int l  = blockIdx.x * 4 + (threadIdx.x >> 6);
    const int lane = threadIdx.x & 63;
    float* row = sc + ((size_t)bb * 4000 + l) * 256;
    const int* tk = tokens + (size_t)(b0 + bb) * 256;
    float4 v = *(const float4*)&row[lane * 4];
    const int4 tv = *(const int4*)&tk[lane * 4];
    if (tv.x == 0) v.x = -1e9f;
    if (tv.y == 0) v.y = -1e9f;
    if (tv.z == 0) v.z = -1e9f;
    if (tv.w == 0) v.w = -1e9f;
    float mx = fmaxf(fmaxf(v.x, v.y), fmaxf(v.z, v.w));
    for (int o = 32; o > 0; o >>= 1) mx = fmaxf(mx, __shfl_xor(mx, o));
    v.x = __expf(v.x - mx); v.y = __expf(v.y - mx);
    v.z = __expf(v.z - mx); v.w = __expf(v.w - mx);
    float s = v.x + v.y + v.z + v.w;
    for (int o = 32; o > 0; o >>= 1) s += __shfl_xor(s, o);
    const float inv = 1.f / s;
    const float p0 = v.x * inv, p1 = v.y * inv, p2 = v.z * inv, p3 = v.w * inv;
    const ushort h0 = f2bf(p0), h1 = f2bf(p1), h2 = f2bf(p2), h3 = f2bf(p3);
    const ushort l0 = f2bf(p0 - bf2f(h0)), l1 = f2bf(p1 - bf2f(h1));
    const ushort l2 = f2bf(p2 - bf2f(h2)), l3 = f2bf(p3 - bf2f(h3));
    ushort* orow = (ushort*)row;
    uint2 hw, lw;
    hw.x = (unsigned)h0 | ((unsigned)h1 << 16);
    hw.y = (unsigned)h2 | ((unsigned)h3 << 16);
    lw.x = (unsigned)l0 | ((unsigned)l1 << 16);
    lw.y = (unsigned)l2 | ((unsigned)l3 << 16);
    *(uint2*)&orow[lane * 4] = hw;
    *(uint2*)&orow[256 + lane * 4] = lw;
}

// ---------------------------------------------------------------------------
// Sparse GCN aggregation.
// ---------------------------------------------------------------------------
__global__ __launch_bounds__(256) void spmm_k(
    const float* __restrict__ adj, const float* __restrict__ tmp,
    const float* __restrict__ bias, float* __restrict__ outp)
{
    const int l = blockIdx.x;
    __shared__ int   idxs[4][256];
    __shared__ float vals[4][256];
    __shared__ int   cnts[4];
    const int t = threadIdx.x;
    const int w = t >> 6, lane = t & 63;
    const float* arow = adj + (size_t)l * 4000;
    int cnt = 0;
    for (int r = 0; r < 16; ++r) {
        const int o = r * 64 + lane;
        const int j = w * 1000 + o;
        const float a = (o < 1000) ? arow[j] : 0.f;
        const unsigned long long mk = __ballot(a != 0.f);
        if (a != 0.f) {
            const int pos = cnt + __popcll(mk & ((1ull << lane) - 1ull));
            if (pos < 256) { idxs[w][pos] = j; vals[w][pos] = a; }
        }
        cnt += __popcll(mk);
    }
    if (lane == 0) cnts[w] = min(cnt, 256);
    __syncthreads();
    const int c0 = t * 2;
    float a0 = 0.f, a1 = 0.f;
    for (int ww = 0; ww < 4; ++ww) {
        const int n = cnts[ww];
        for (int e = 0; e < n; ++e) {
            const float a = vals[ww][e];
            const float2 tv = *(const float2*)&tmp[(size_t)idxs[ww][e] * 512 + c0];
            a0 = fmaf(a, tv.x, a0);
            a1 = fmaf(a, tv.y, a1);
        }
    }
    float2 res;
    res.x = fmaxf(a0 + bias[c0], 0.f);
    res.y = fmaxf(a1 + bias[c0 + 1], 0.f);
    *(float2*)&outp[(size_t)l * 512 + c0] = res;
}

// ---------------------------------------------------------------------------
// Final projection.
// ---------------------------------------------------------------------------
__global__ __launch_bounds__(256) void out_k(
    const float* __restrict__ x2, const float* __restrict__ w_out,
    const float* __restrict__ b_out, float* __restrict__ outp, int b0)
{
    const int r = blockIdx.x * 4 + (threadIdx.x >> 6);
    const int lane = threadIdx.x & 63;
    const float4 xv = *(const float4*)&x2[(size_t)r * 256 + lane * 4];
    const float4 wv = *(const float4*)&w_out[lane * 4];
    float s = xv.x * wv.x + xv.y * wv.y + xv.z * wv.z + xv.w * wv.w;
    for (int o = 32; o > 0; o >>= 1) s += __shfl_xor(s, o);
    if (lane == 0) {
        const int bb = r / 4000, l = r - bb * 4000;
        outp[(size_t)(b0 + bb) * 4000 + l] = s + b_out[0];
    }
}

// ---------------------------------------------------------------------------
extern "C" void kernel_launch(void* const* d_in, const int* in_sizes, int n_in,
                              void* d_out, int out_size, void* d_ws, size_t ws_size,
                              hipStream_t stream)
{
    const int*   tokens    = (const int*)  d_in[0];
    const float* emb       = (const float*)d_in[1];
    const float* w_ih_f    = (const float*)d_in[2];
    const float* w_hh_f    = (const float*)d_in[3];
    const float* b_f       = (const float*)d_in[4];
    const float* w_ih_b    = (const float*)d_in[5];
    const float* w_hh_b    = (const float*)d_in[6];
    const float* b_b       = (const float*)d_in[7];
    const float* attn_w    = (const float*)d_in[8];
    const float* label_emb = (const float*)d_in[9];
    const float* adj       = (const float*)d_in[10];
    const float* gcn_w     = (const float*)d_in[11];
    const float* gcn_b     = (const float*)d_in[12];
    const float* w1        = (const float*)d_in[13];
    const float* b1        = (const float*)d_in[14];
    const float* w2        = (const float*)d_in[15];
    const float* b2        = (const float*)d_in[16];
    const float* w_out     = (const float*)d_in[17];
    const float* b_out     = (const float*)d_in[18];
    float* outp = (float*)d_out;
    float* wsf  = (float*)d_ws;

    // ---- workspace layout (float offsets) ----
    const size_t off_gf  = 0;          // gates_f 8.39M
    const size_t off_gb  = 8388608;    // gates_b 8.39M
    const size_t off_rnn = 16777216;   // rnn fp32 4.19M
    const size_t off_tmp = 20971520;   // gcn_tmp 2.05M (lstm hbuf/stamp overlay)
    const size_t off_go  = 23019520;   // gcn_out 2.05M
    const size_t off_ctr = 25067520;   // contrib 2.05M
    const size_t base_end = 27115520;
    const size_t S_sz = 10829824;
    const size_t have = ws_size / 4;
    int NB = 1; size_t offS = off_gf, offC = off_gf + S_sz;
    {
        const int tiers[6] = {32, 16, 8, 4, 2, 0};
        bool found = false;
        for (int t = 0; tiers[t]; ++t) {
            if (have >= base_end + S_sz + (size_t)tiers[t] * 5120000) {
                NB = tiers[t]; offS = base_end; offC = base_end + S_sz; found = true; break;
            }
        }
        if (!found && have >= base_end + S_sz) { NB = 2; offS = base_end; offC = off_gf; }
    }

    float* gates_f = wsf + off_gf;
    float* gates_b = wsf + off_gb;
    float* rnn     = wsf + off_rnn;
    float* gcn_tmp = wsf + off_tmp;
    float* gcn_out = wsf + off_go;
    float* contrib = wsf + off_ctr;
    float* hbuf    = wsf + off_tmp;                  // [2][64][256] overlay
    int*   stamp   = (int*)(wsf + off_tmp + 32768);  // [64][64] overlay (16KB)

    // pre-lstm split staging (dead before its host region is reused)
    const size_t off_esp = (offS == off_gf) ? off_rnn : offS;
    ushort* esplit  = (ushort*)(wsf + off_esp);
    ushort* wsplitf = esplit + (size_t)8192 * 640;
    ushort* wsplitb = wsplitf + (size_t)1024 * 640;

    ushort* attn_ws16 = (ushort*)(wsf + offS);                // [4000][1024]
    ushort* w1t16     = (ushort*)(wsf + offS + 2048000);      // [512][1024]
    ushort* w2t16     = (ushort*)(wsf + offS + 2310144);      // [256][1024]
    ushort* rnn_nt16  = (ushort*)(wsf + offS + 2441216);      // [32][256][1024]
    ushort* rnnT16    = (ushort*)(wsf + offS + 6635520);      // [32][512][512]

    float*  scoresb = wsf + offC;
    ushort* attn16  = (ushort*)(wsf + offC + (size_t)NB * 1024000);
    ushort* x116    = (ushort*)(wsf + offC + (size_t)NB * 1024000 + (size_t)NB * 2048000);
    float*  x2b     = scoresb;

    // GCN split staging, overlays the chunk region (dead before head loop)
    ushort* le16   = (ushort*)(wsf + offC);                   // [4000][512]
    ushort* gw16   = le16 + (size_t)4000 * 512;               // [512][512]
    ushort* go16   = gw16 + (size_t)512 * 512;                // [4000][1024]
    ushort* w1b16  = go16 + (size_t)4000 * 1024;              // [512][1024]

    // 0. zero lstm sub-stamps (graph-replay safe)
    init_cnt_k<<<16, 256, 0, stream>>>(stamp);

    // 1. input projections on MFMA
    gsplit_k<<<8192, 256, 0, stream>>>(emb, tokens, esplit, 300, 320);
    gsplit_k<<<1024, 256, 0, stream>>>(w_ih_f, nullptr, wsplitf, 300, 320);
    gsplit_k<<<1024, 256, 0, stream>>>(w_ih_b, nullptr, wsplitb, 300, 320);
    mgemm_k<true, false, false, true, false><<<dim3(64, 8, 1), 256, 0, stream>>>(
        esplit, wsplitf, gates_f, nullptr,
        8192, 1024, 320, 640, 640, 1024, 0,
        0L, 0L, 0L, 0L, b_f, nullptr, 1, 0);
    mgemm_k<true, false, false, true, false><<<dim3(64, 8, 1), 256, 0, stream>>>(
        esplit, wsplitb, gates_b, nullptr,
        8192, 1024, 320, 640, 640, 1024, 0,
        0L, 0L, 0L, 0L, b_b, nullptr, 1, 0);

    // 2. biLSTM scan -> rnn [B,S,512] (per-wave sub-stamp protocol)
    lstm_reg_k<<<dim3(64, 4), 1024, 0, stream>>>(
        gates_f, gates_b, w_hh_f, w_hh_b, rnn, hbuf, stamp);

    // 3. split conversions for the head
    split_k<<<16384, 256, 0, stream>>>(rnn, rnn_nt16, 8192, 512);
    tsplit_k<<<dim3(8, 4, 32), 256, 0, stream>>>(rnn, rnnT16, 256, 512, 512, 131072, 262144);
    split_k<<<8000, 256, 0, stream>>>(attn_w, attn_ws16, 4000, 512);
    tsplit_k<<<dim3(8, 8, 1), 256, 0, stream>>>(w1, w1t16, 512, 512, 512, 0, 0);
    tsplit_k<<<dim3(4, 8, 1), 256, 0, stream>>>(w2, w2t16, 512, 256, 256, 0, 0);

    // 4. GCN branch on MFMA (runs after lstm in stream order; hbuf region dead)
    split_k<<<4000, 256, 0, stream>>>(label_emb, le16, 4000, 256);
    tsplit_k<<<dim3(8, 4, 1), 256, 0, stream>>>(gcn_w, gw16, 256, 512, 512, 0, 0);
    mgemm_k<false, false, false, true, false><<<dim3(32, 4, 1), 256, 0, stream>>>(
        le16, gw16, gcn_tmp, nullptr,
        4000, 512, 256, 512, 512, 512, 0,
        0L, 0L, 0L, 0L, nullptr, nullptr, 1, 0);
    spmm_k<<<dim3(4000), 256, 0, stream>>>(adj, gcn_tmp, gcn_b, gcn_out);
    split_k<<<8000, 256, 0, stream>>>(gcn_out, go16, 4000, 512);
    tsplit_k<<<dim3(8, 8, 1), 256, 0, stream>>>(w1 + (size_t)512 * 512, w1b16, 512, 512, 512, 0, 0);
    mgemm_k<true, false, false, true, false><<<dim3(32, 4, 1), 256, 0, stream>>>(
        go16, w1b16, contrib, nullptr,
        4000, 512, 512, 1024, 1024, 512, 0,
        0L, 0L, 0L, 0L, b1, nullptr, 1, 0);

    // 5. attention + MLP head (MFMA split-bf16), chunked over batch
    for (int b0 = 0; b0 < 32; b0 += NB) {
        const int nb = (32 - b0 < NB) ? (32 - b0) : NB;
        mgemm_k<false, false, false, true, false><<<dim3(32, 2, nb), 256, 0, stream>>>(
            attn_ws16, rnn_nt16 + (size_t)b0 * 262144, scoresb, nullptr,
            4000, 256, 512, 1024, 1024, 256, 0,
            0L, 262144L, 1024000L, 0L, nullptr, nullptr, 1, 0);
        softmax_split_k<<<dim3(1000, nb), 256, 0, stream>>>(scoresb, tokens, b0);
        mgemm_k<false, false, false, false, true><<<dim3(32, 4, nb), 256, 0, stream>>>(
            (const ushort*)scoresb, rnnT16 + (size_t)b0 * 262144, nullptr, attn16,
            4000, 512, 256, 512, 512, 0, 1024,
            2048000L, 262144L, 0L, 4096000L, nullptr, nullptr, 1, 0);
        mgemm_k<false, true, true, false, true><<<dim3((nb * 4000 + 127) / 128, 4, 1), 256, 0, stream>>>(
            attn16, w1t16, nullptr, x116,
            nb * 4000, 512, 512, 1024, 1024, 0, 1024,
            0L, 0L, 0L, 0L, nullptr, contrib, 4000, 512);
        mgemm_k<true, false, true, true, false><<<dim3((nb * 4000 + 127) / 128, 2, 1), 256, 0, stream>>>(
            x116, w2t16, x2b, nullptr,
            nb * 4000, 256, 512, 1024, 1024, 256, 0,
            0L, 0L, 0L, 0L, b2, nullptr, 1, 0);
        out_k<<<dim3(nb * 1000), 256, 0, stream>>>(x2b, w_out, b_out, outp, b0);
    }
}

// Round 12
// 1767.651 us; speedup vs baseline: 1.2089x; 1.2089x over previous
//
#include <hip/hip_runtime.h>
#include <hip/hip_bf16.h>
#include <math.h>

// Problem constants
// B=32 S=256 E=300 H=256(4H=1024) L=4000 D=256 G=512 V=50000 LIN1=512 LIN2=256, 2H=512

typedef __attribute__((ext_vector_type(8))) short bfrag;   // 8 bf16 (4 VGPRs)
typedef __attribute__((ext_vector_type(4))) float ffrag;   // 4 fp32 acc

__device__ __forceinline__ ushort f2bf(float x) {
    union { float f; unsigned u; } c; c.f = x;
    const unsigned r = c.u + 0x7fffu + ((c.u >> 16) & 1u);
    return (ushort)(r >> 16);
}
__device__ __forceinline__ float bf2f(ushort h) {
    union { unsigned u; float f; } c; c.u = (unsigned)h << 16;
    return c.f;
}

// ---------------------------------------------------------------------------
// Split-bf16 MFMA GEMM: C = A * B^T via 3-term split (hh + hl + lh).
// A: [M][lda] bf16, row = [hi(0..K) | lo(0..K)]; B likewise. Tile 128x128,
// BK=32, 4 waves (2x2 of 64x64). LDS rows padded to 40 bf16 (80B stride).
// Pipeline: next-tile loads issued before the MFMA phase (latency hides).
// [Measured best. R10 lesson: gload_lds+linear-LDS regressed (bank parity +
// lost prefetch). R11 lesson: leave this kernel alone while lstm changes.]
// ---------------------------------------------------------------------------
template<bool BIAS, bool ADDROW, bool RELU, bool OUTF, bool OUTS>
__global__ __launch_bounds__(256) void mgemm_k(
    const ushort* __restrict__ A, const ushort* __restrict__ B,
    float* __restrict__ Cf, ushort* __restrict__ Cs,
    int M, int N, int K, int lda, int ldb, int ldc, int ldcs,
    long abs_, long bbs_, long cbs_, long csbs_,
    const float* __restrict__ bias,
    const float* __restrict__ addrow, int addmod, int ldadd)
{
    const int tid = threadIdx.x;
    const int ln = tid & 63;
    const int wv = tid >> 6;
    const int wm = wv >> 1, wn = wv & 1;
    const int m0 = blockIdx.x * 128, n0 = blockIdx.y * 128;
    const int z = blockIdx.z;
    A += (size_t)z * abs_;
    B += (size_t)z * bbs_;

    __shared__ ushort Ah[128 * 40], Al[128 * 40], Bh[128 * 40], Bl[128 * 40];

    ffrag acc[4][4];
#pragma unroll
    for (int i = 0; i < 4; ++i)
#pragma unroll
        for (int j = 0; j < 4; ++j) acc[i][j] = ffrag{0.f, 0.f, 0.f, 0.f};

    const int sr = tid >> 1;
    const int sk = (tid & 1) * 16;
    const int am = min(m0 + sr, M - 1);
    const int bn = n0 + sr;
    const int fr = ln & 15;
    const int fk = (ln >> 4) * 8;

    const ushort* arow = A + (size_t)am * lda + sk;
    const ushort* brow = B + (size_t)bn * ldb + sk;

    bfrag ah0, ah1, al0, al1, bh0, bh1, bl0, bl1;
    {
        const ushort* ap = arow;
        const ushort* bp = brow;
        ah0 = *(const bfrag*)ap;       ah1 = *(const bfrag*)(ap + 8);
        al0 = *(const bfrag*)(ap + K); al1 = *(const bfrag*)(ap + K + 8);
        bh0 = *(const bfrag*)bp;       bh1 = *(const bfrag*)(bp + 8);
        bl0 = *(const bfrag*)(bp + K); bl1 = *(const bfrag*)(bp + K + 8);
    }

    for (int k0 = 0; k0 < K; k0 += 32) {
        __syncthreads();   // previous iteration's frag reads complete
        *(bfrag*)&Ah[sr * 40 + sk] = ah0;  *(bfrag*)&Ah[sr * 40 + sk + 8] = ah1;
        *(bfrag*)&Al[sr * 40 + sk] = al0;  *(bfrag*)&Al[sr * 40 + sk + 8] = al1;
        *(bfrag*)&Bh[sr * 40 + sk] = bh0;  *(bfrag*)&Bh[sr * 40 + sk + 8] = bh1;
        *(bfrag*)&Bl[sr * 40 + sk] = bl0;  *(bfrag*)&Bl[sr * 40 + sk + 8] = bl1;
        __syncthreads();   // tile staged
        if (k0 + 32 < K) {  // issue next-tile loads early
            const ushort* ap = arow + k0 + 32;
            const ushort* bp = brow + k0 + 32;
            ah0 = *(const bfrag*)ap;       ah1 = *(const bfrag*)(ap + 8);
            al0 = *(const bfrag*)(ap + K); al1 = *(const bfrag*)(ap + K + 8);
            bh0 = *(const bfrag*)bp;       bh1 = *(const bfrag*)(bp + 8);
            bl0 = *(const bfrag*)(bp + K); bl1 = *(const bfrag*)(bp + K + 8);
        }
        bfrag afh[4], afl[4];
#pragma unroll
        for (int i = 0; i < 4; ++i) {
            const int ar = (wm * 64 + i * 16 + fr) * 40 + fk;
            afh[i] = *(const bfrag*)&Ah[ar];
            afl[i] = *(const bfrag*)&Al[ar];
        }
#pragma unroll
        for (int j = 0; j < 4; ++j) {
            const int br = (wn * 64 + j * 16 + fr) * 40 + fk;
            const bfrag bfh = *(const bfrag*)&Bh[br];
            const bfrag bfl = *(const bfrag*)&Bl[br];
#pragma unroll
            for (int i = 0; i < 4; ++i) {
                acc[i][j] = __builtin_amdgcn_mfma_f32_16x16x32_bf16(afh[i], bfh, acc[i][j], 0, 0, 0);
                acc[i][j] = __builtin_amdgcn_mfma_f32_16x16x32_bf16(afh[i], bfl, acc[i][j], 0, 0, 0);
                acc[i][j] = __builtin_amdgcn_mfma_f32_16x16x32_bf16(afl[i], bfh, acc[i][j], 0, 0, 0);
            }
        }
    }

#pragma unroll
    for (int i = 0; i < 4; ++i) {
#pragma unroll
        for (int rg = 0; rg < 4; ++rg) {
            const int gm = m0 + wm * 64 + i * 16 + (ln >> 4) * 4 + rg;
            if (gm >= M) continue;
            const float* addp = ADDROW ? (addrow + (size_t)(gm % addmod) * ldadd) : nullptr;
#pragma unroll
            for (int j = 0; j < 4; ++j) {
                const int gn = n0 + wn * 64 + j * 16 + fr;
                float v = acc[i][j][rg];
                if (BIAS) v += bias[gn];
                if (ADDROW) v += addp[gn];
                if (RELU) v = fmaxf(v, 0.f);
                if (OUTF) Cf[(size_t)z * cbs_ + (size_t)gm * ldc + gn] = v;
                if (OUTS) {
                    const ushort h = f2bf(v);
                    const ushort l = f2bf(v - bf2f(h));
                    ushort* cp = Cs + (size_t)z * csbs_ + (size_t)gm * ldcs;
                    cp[gn] = h;
                    cp[N + gn] = l;
                }
            }
        }
    }
}

// ---------------------------------------------------------------------------
// Gather(optional) + split + zero-pad: row r of src (K cols) -> [r][2*Kpad]
// ---------------------------------------------------------------------------
__global__ void gsplit_k(const float* __restrict__ src, const int* __restrict__ tok,
                         ushort* __restrict__ outp, int K, int Kpad)
{
    const int r = blockIdx.x;
    const float* s = src + (size_t)(tok ? tok[r] : r) * K;
    ushort* o = outp + (size_t)r * 2 * Kpad;
    for (int k = threadIdx.x; k < Kpad; k += blockDim.x) {
        const float x = (k < K) ? s[k] : 0.f;
        const ushort h = f2bf(x);
        const ushort l = f2bf(x - bf2f(h));
        o[k] = h;
        o[Kpad + k] = l;
    }
}

// ---------------------------------------------------------------------------
// fp32 [rows][K] -> split bf16 [rows][2K] (hi | lo)
// ---------------------------------------------------------------------------
__global__ void split_k(const float* __restrict__ in, ushort* __restrict__ outp,
                        int rows, int K)
{
    const int i = blockIdx.x * 256 + threadIdx.x;
    if (i >= rows * K) return;
    const int r = i / K, k = i - r * K;
    const float x = in[i];
    const ushort h = f2bf(x);
    const ushort l = f2bf(x - bf2f(h));
    ushort* o = outp + (size_t)r * 2 * K;
    o[k] = h;
    o[K + k] = l;
}

// ---------------------------------------------------------------------------
// fp32 [R][C] -> split-transposed bf16 [C][2R]
// ---------------------------------------------------------------------------
__global__ __launch_bounds__(256) void tsplit_k(
    const float* __restrict__ in, ushort* __restrict__ outp,
    int R, int C, int ldin, long ibs, long obs)
{
    __shared__ float t[64][65];
    const int c0 = blockIdx.x * 64, r0 = blockIdx.y * 64;
    in   += (size_t)blockIdx.z * ibs;
    outp += (size_t)blockIdx.z * obs;
    const int tx = threadIdx.x & 15, ty = threadIdx.x >> 4;
#pragma unroll
    for (int i = 0; i < 4; ++i) {
        const int r = ty * 4 + i;
        const float4 v = *(const float4*)&in[(size_t)(r0 + r) * ldin + c0 + tx * 4];
        t[tx * 4 + 0][r] = v.x;
        t[tx * 4 + 1][r] = v.y;
        t[tx * 4 + 2][r] = v.z;
        t[tx * 4 + 3][r] = v.w;
    }
    __syncthreads();
    const int R2 = 2 * R;
#pragma unroll
    for (int i = 0; i < 4; ++i) {
        const int c = ty * 4 + i;
        ushort h[4], l[4];
#pragma unroll
        for (int k2 = 0; k2 < 4; ++k2) {
            const float x = t[c][tx * 4 + k2];
            h[k2] = f2bf(x);
            l[k2] = f2bf(x - bf2f(h[k2]));
        }
        uint2 hw, lw;
        hw.x = (unsigned)h[0] | ((unsigned)h[1] << 16);
        hw.y = (unsigned)h[2] | ((unsigned)h[3] << 16);
        lw.x = (unsigned)l[0] | ((unsigned)l[1] << 16);
        lw.y = (unsigned)l[2] | ((unsigned)l[3] << 16);
        *(uint2*)&outp[(size_t)(c0 + c) * R2 + r0 + tx * 4] = hw;
        *(uint2*)&outp[(size_t)(c0 + c) * R2 + R + r0 + tx * 4] = lw;
    }
}

// ---------------------------------------------------------------------------
// Register-resident biLSTM scan: R7 stamp protocol (measured best, 622us).
// [R8/R11 lessons: distributed spins (per-thread tagged-h, per-wave
// sub-stamps) flood the coherence point and regress 18-66%. Keep the
// single-poller design: tid0 polls 4 stamps, everyone else parks at B1.]
// R12 change: rnn HBM store moved AFTER the stamp publication — B3's
// vmcnt(0) drain now waits only on the h L3-atomic ack, not the slower
// HBM write ack; the rnn ack drains hidden under the next step's poll+B1.
// Co-residency: 256 blocks <= 256 CUs (1 block/CU) => no deadlock.
// ---------------------------------------------------------------------------
__global__ __launch_bounds__(1024) void lstm_reg_k(
    const float* __restrict__ gxf, const float* __restrict__ gxb,
    const float* __restrict__ whf, const float* __restrict__ whb,
    float* __restrict__ rnn, float* hbuf, int* stamp)
{
    const int p = blockIdx.x;          // pair: batch b=p>>1, dir=p&1
    const int q = blockIdx.y;          // quarter (owns units [64q,64q+64))
    const int b = p >> 1, dir = p & 1;
    const float* xg = dir ? gxb : gxf;
    const float* W  = dir ? whb : whf;
    const int tid = threadIdx.x;
    const int wv = tid >> 6, lane = tid & 63;
    const int ul = lane >> 4;           // unit-local 0..3
    const int ks = (lane >> 2) & 3;     // 64-float k-slice
    const int gt = lane & 3;            // gate 0..3 (i,f,g,o)
    const int u  = wv * 4 + ul;         // block unit 0..63
    const int grow = gt * 256 + q * 64 + u;

    float4 w[16];
    {
        const float4* wp = (const float4*)(W + (size_t)grow * 256 + ks * 64);
#pragma unroll
        for (int i = 0; i < 16; ++i) w[i] = wp[i];
    }

    __shared__ float h_lds[4 * 68];
    __shared__ float xg_lds[320];       // [u*5 + gt], stride 5 = conflict-free

    float* hb0 = hbuf + (size_t)p * 256;            // parity 0
    float* hb1 = hbuf + (size_t)(64 + p) * 256;     // parity 1
    int* sp = stamp + p * 16;

    const size_t xgb = (size_t)b * 256;
    const int g2 = (tid >> 6) * 256 + q * 64 + (tid & 63);  // staging map (tid<256)
    float c = 0.f;                                   // redundant in all lanes
    float xg_cur = 0.f;
    if (tid < 256) xg_cur = xg[(xgb + (dir ? 255 : 0)) * 1024 + g2];

    for (int st = 0; st < 256; ++st) {
        const int ts = dir ? 255 - st : st;
        if (st > 0 && tid == 0) {
            while (true) {
                int s0 = __hip_atomic_load(&sp[0], __ATOMIC_RELAXED, __HIP_MEMORY_SCOPE_AGENT);
                int s1 = __hip_atomic_load(&sp[1], __ATOMIC_RELAXED, __HIP_MEMORY_SCOPE_AGENT);
                int s2 = __hip_atomic_load(&sp[2], __ATOMIC_RELAXED, __HIP_MEMORY_SCOPE_AGENT);
                int s3 = __hip_atomic_load(&sp[3], __ATOMIC_RELAXED, __HIP_MEMORY_SCOPE_AGENT);
                if (min(min(s0, s1), min(s2, s3)) >= st) break;
            }
        }
        __syncthreads();   // B1: partners' h[st-1] published (via atomics);
                           //     also drains prev step's rnn store (hidden)
        if (tid < 256) {
            float hv = 0.f;
            if (st > 0) {
                const float* src = (st & 1) ? hb0 : hb1;   // parity (st-1)&1
                hv = __hip_atomic_load(&src[tid], __ATOMIC_RELAXED, __HIP_MEMORY_SCOPE_AGENT);
            }
            h_lds[(tid >> 6) * 68 + (tid & 63)] = hv;
            xg_lds[(tid & 63) * 5 + (tid >> 6)] = xg_cur;  // [u][gt] stride-5
        }
        __syncthreads();   // B2: h_lds/xg_lds ready
        float acc = 0.f;
        {
            const float4* hp = (const float4*)&h_lds[ks * 68];
#pragma unroll
            for (int i = 0; i < 16; ++i) {
                const float4 hv = hp[i];
                acc = fmaf(w[i].x, hv.x, acc);
                acc = fmaf(w[i].y, hv.y, acc);
                acc = fmaf(w[i].z, hv.z, acc);
                acc = fmaf(w[i].w, hv.w, acc);
            }
        }
        acc += __shfl_xor(acc, 4);      // reduce over ks (bits 2-3)
        acc += __shfl_xor(acc, 8);
        const float g = acc + xg_lds[u * 5 + gt];
        // gather quartet gates via xor-shfls; all lanes act redundantly
        const float t1 = __shfl_xor(g, 1);
        const float t2 = __shfl_xor(g, 2);
        const float t3 = __shfl_xor(t1, 2);
        const float g0 = (gt == 0) ? g : (gt == 1) ? t1 : (gt == 2) ? t2 : t3;
        const float g1 = (gt == 1) ? g : (gt == 0) ? t1 : (gt == 3) ? t2 : t3;
        const float g2v = (gt == 2) ? g : (gt == 3) ? t1 : (gt == 0) ? t2 : t3;
        const float g3v = (gt == 3) ? g : (gt == 2) ? t1 : (gt == 1) ? t2 : t3;
        const float si = 1.f / (1.f + __expf(-g0));
        const float sf = 1.f / (1.f + __expf(-g1));
        const float so = 1.f / (1.f + __expf(-g3v));
        const float tg = 1.f - 2.f / (__expf(2.f * g2v) + 1.f);
        c = sf * c + si * tg;
        const float tc = 1.f - 2.f / (__expf(2.f * c) + 1.f);
        const float hn = so * tc;
        const bool writer = ((lane & 15) == 0);      // ks==0 && gt==0
        if (writer) {                    // h publish only (L3 atomic ack)
            float* dst = (st & 1) ? hb1 : hb0;       // parity st&1
            __hip_atomic_store(&dst[q * 64 + u], hn, __ATOMIC_RELAXED, __HIP_MEMORY_SCOPE_AGENT);
        }
        __syncthreads();   // B3: drains h atomic acks only (rnn not yet issued)
        if (tid == 0) {
            __hip_atomic_store(&sp[q], st + 1, __ATOMIC_RELAXED, __HIP_MEMORY_SCOPE_AGENT);
        }
        // off-chain: rnn HBM store (ack drains at next step's B1) + xg prefetch
        if (writer) {
            rnn[(xgb + ts) * 512 + (size_t)dir * 256 + q * 64 + u] = hn;
        }
        if (tid < 256 && st < 255) {
            const int tsn = dir ? 254 - st : st + 1;
            xg_cur = xg[(xgb + tsn) * 1024 + g2];
        }
    }
}

__global__ void init_cnt_k(int* stamp) {
    const int i = blockIdx.x * blockDim.x + threadIdx.x;
    if (i < 1024) stamp[i] = 0;
}

// ---------------------------------------------------------------------------
// Masked softmax over s (256); writes split-bf16 probs in place.
// ---------------------------------------------------------------------------
__global__ __launch_bounds__(256) void softmax_split_k(
    float* __restrict__ sc, const int* __restrict__ tokens, int b0)
{
    const int bb = blockIdx.y;
    const int l  = blockIdx.x * 4 + (threadIdx.x >> 6);
    const int lane = threadIdx.x & 63;
    float* row = sc + ((size_t)bb * 4000 + l) * 256;
    const int* tk = tokens + (size_t)(b0 + bb) * 256;
    float4 v = *(const float4*)&row[lane * 4];
    const int4 tv = *(const int4*)&tk[lane * 4];
    if (tv.x == 0) v.x = -1e9f;
    if (tv.y == 0) v.y = -1e9f;
    if (tv.z == 0) v.z = -1e9f;
    if (tv.w == 0) v.w = -1e9f;
    float mx = fmaxf(fmaxf(v.x, v.y), fmaxf(v.z, v.w));
    for (int o = 32; o > 0; o >>= 1) mx = fmaxf(mx, __shfl_xor(mx, o));
    v.x = __expf(v.x - mx); v.y = __expf(v.y - mx);
    v.z = __expf(v.z - mx); v.w = __expf(v.w - mx);
    float s = v.x + v.y + v.z + v.w;
    for (int o = 32; o > 0; o >>= 1) s += __shfl_xor(s, o);
    const float inv = 1.f / s;
    const float p0 = v.x * inv, p1 = v.y * inv, p2 = v.z * inv, p3 = v.w * inv;
    const ushort h0 = f2bf(p0), h1 = f2bf(p1), h2 = f2bf(p2), h3 = f2bf(p3);
    const ushort l0 = f2bf(p0 - bf2f(h0)), l1 = f2bf(p1 - bf2f(h1));
    const ushort l2 = f2bf(p2 - bf2f(h2)), l3 = f2bf(p3 - bf2f(h3));
    ushort* orow = (ushort*)row;
    uint2 hw, lw;
    hw.x = (unsigned)h0 | ((unsigned)h1 << 16);
    hw.y = (unsigned)h2 | ((unsigned)h3 << 16);
    lw.x = (unsigned)l0 | ((unsigned)l1 << 16);
    lw.y = (unsigned)l2 | ((unsigned)l3 << 16);
    *(uint2*)&orow[lane * 4] = hw;
    *(uint2*)&orow[256 + lane * 4] = lw;
}

// ---------------------------------------------------------------------------
// Sparse GCN aggregation.
// ---------------------------------------------------------------------------
__global__ __launch_bounds__(256) void spmm_k(
    const float* __restrict__ adj, const float* __restrict__ tmp,
    const float* __restrict__ bias, float* __restrict__ outp)
{
    const int l = blockIdx.x;
    __shared__ int   idxs[4][256];
    __shared__ float vals[4][256];
    __shared__ int   cnts[4];
    const int t = threadIdx.x;
    const int w = t >> 6, lane = t & 63;
    const float* arow = adj + (size_t)l * 4000;
    int cnt = 0;
    for (int r = 0; r < 16; ++r) {
        const int o = r * 64 + lane;
        const int j = w * 1000 + o;
        const float a = (o < 1000) ? arow[j] : 0.f;
        const unsigned long long mk = __ballot(a != 0.f);
        if (a != 0.f) {
            const int pos = cnt + __popcll(mk & ((1ull << lane) - 1ull));
            if (pos < 256) { idxs[w][pos] = j; vals[w][pos] = a; }
        }
        cnt += __popcll(mk);
    }
    if (lane == 0) cnts[w] = min(cnt, 256);
    __syncthreads();
    const int c0 = t * 2;
    float a0 = 0.f, a1 = 0.f;
    for (int ww = 0; ww < 4; ++ww) {
        const int n = cnts[ww];
        for (int e = 0; e < n; ++e) {
            const float a = vals[ww][e];
            const float2 tv = *(const float2*)&tmp[(size_t)idxs[ww][e] * 512 + c0];
            a0 = fmaf(a, tv.x, a0);
            a1 = fmaf(a, tv.y, a1);
        }
    }
    float2 res;
    res.x = fmaxf(a0 + bias[c0], 0.f);
    res.y = fmaxf(a1 + bias[c0 + 1], 0.f);
    *(float2*)&outp[(size_t)l * 512 + c0] = res;
}

// ---------------------------------------------------------------------------
// Final projection.
// ---------------------------------------------------------------------------
__global__ __launch_bounds__(256) void out_k(
    const float* __restrict__ x2, const float* __restrict__ w_out,
    const float* __restrict__ b_out, float* __restrict__ outp, int b0)
{
    const int r = blockIdx.x * 4 + (threadIdx.x >> 6);
    const int lane = threadIdx.x & 63;
    const float4 xv = *(const float4*)&x2[(size_t)r * 256 + lane * 4];
    const float4 wv = *(const float4*)&w_out[lane * 4];
    float s = xv.x * wv.x + xv.y * wv.y + xv.z * wv.z + xv.w * wv.w;
    for (int o = 32; o > 0; o >>= 1) s += __shfl_xor(s, o);
    if (lane == 0) {
        const int bb = r / 4000, l = r - bb * 4000;
        outp[(size_t)(b0 + bb) * 4000 + l] = s + b_out[0];
    }
}

// ---------------------------------------------------------------------------
extern "C" void kernel_launch(void* const* d_in, const int* in_sizes, int n_in,
                              void* d_out, int out_size, void* d_ws, size_t ws_size,
                              hipStream_t stream)
{
    const int*   tokens    = (const int*)  d_in[0];
    const float* emb       = (const float*)d_in[1];
    const float* w_ih_f    = (const float*)d_in[2];
    const float* w_hh_f    = (const float*)d_in[3];
    const float* b_f       = (const float*)d_in[4];
    const float* w_ih_b    = (const float*)d_in[5];
    const float* w_hh_b    = (const float*)d_in[6];
    const float* b_b       = (const float*)d_in[7];
    const float* attn_w    = (const float*)d_in[8];
    const float* label_emb = (const float*)d_in[9];
    const float* adj       = (const float*)d_in[10];
    const float* gcn_w     = (const float*)d_in[11];
    const float* gcn_b     = (const float*)d_in[12];
    const float* w1        = (const float*)d_in[13];
    const float* b1        = (const float*)d_in[14];
    const float* w2        = (const float*)d_in[15];
    const float* b2        = (const float*)d_in[16];
    const float* w_out     = (const float*)d_in[17];
    const float* b_out     = (const float*)d_in[18];
    float* outp = (float*)d_out;
    float* wsf  = (float*)d_ws;

    // ---- workspace layout (float offsets) ----
    const size_t off_gf  = 0;          // gates_f 8.39M
    const size_t off_gb  = 8388608;    // gates_b 8.39M
    const size_t off_rnn = 16777216;   // rnn fp32 4.19M
    const size_t off_tmp = 20971520;   // gcn_tmp 2.05M (lstm hbuf/stamp overlay)
    const size_t off_go  = 23019520;   // gcn_out 2.05M
    const size_t off_ctr = 25067520;   // contrib 2.05M
    const size_t base_end = 27115520;
    const size_t S_sz = 10829824;
    const size_t have = ws_size / 4;
    int NB = 1; size_t offS = off_gf, offC = off_gf + S_sz;
    {
        const int tiers[6] = {32, 16, 8, 4, 2, 0};
        bool found = false;
        for (int t = 0; tiers[t]; ++t) {
            if (have >= base_end + S_sz + (size_t)tiers[t] * 5120000) {
                NB = tiers[t]; offS = base_end; offC = base_end + S_sz; found = true; break;
            }
        }
        if (!found && have >= base_end + S_sz) { NB = 2; offS = base_end; offC = off_gf; }
    }

    float* gates_f = wsf + off_gf;
    float* gates_b = wsf + off_gb;
    float* rnn     = wsf + off_rnn;
    float* gcn_tmp = wsf + off_tmp;
    float* gcn_out = wsf + off_go;
    float* contrib = wsf + off_ctr;
    float* hbuf    = wsf + off_tmp;                  // [2][64][256] overlay
    int*   stamp   = (int*)(wsf + off_tmp + 32768);  // [64][16] overlay

    // pre-lstm split staging (dead before its host region is reused)
    const size_t off_esp = (offS == off_gf) ? off_rnn : offS;
    ushort* esplit  = (ushort*)(wsf + off_esp);
    ushort* wsplitf = esplit + (size_t)8192 * 640;
    ushort* wsplitb = wsplitf + (size_t)1024 * 640;

    ushort* attn_ws16 = (ushort*)(wsf + offS);                // [4000][1024]
    ushort* w1t16     = (ushort*)(wsf + offS + 2048000);      // [512][1024]
    ushort* w2t16     = (ushort*)(wsf + offS + 2310144);      // [256][1024]
    ushort* rnn_nt16  = (ushort*)(wsf + offS + 2441216);      // [32][256][1024]
    ushort* rnnT16    = (ushort*)(wsf + offS + 6635520);      // [32][512][512]

    float*  scoresb = wsf + offC;
    ushort* attn16  = (ushort*)(wsf + offC + (size_t)NB * 1024000);
    ushort* x116    = (ushort*)(wsf + offC + (size_t)NB * 1024000 + (size_t)NB * 2048000);
    float*  x2b     = scoresb;

    // GCN split staging, overlays the chunk region (dead before head loop)
    ushort* le16   = (ushort*)(wsf + offC);                   // [4000][512]
    ushort* gw16   = le16 + (size_t)4000 * 512;               // [512][512]
    ushort* go16   = gw16 + (size_t)512 * 512;                // [4000][1024]
    ushort* w1b16  = go16 + (size_t)4000 * 1024;              // [512][1024]

    // 0. zero lstm stamps (graph-replay safe)
    init_cnt_k<<<4, 256, 0, stream>>>(stamp);

    // 1. input projections on MFMA
    gsplit_k<<<8192, 256, 0, stream>>>(emb, tokens, esplit, 300, 320);
    gsplit_k<<<1024, 256, 0, stream>>>(w_ih_f, nullptr, wsplitf, 300, 320);
    gsplit_k<<<1024, 256, 0, stream>>>(w_ih_b, nullptr, wsplitb, 300, 320);
    mgemm_k<true, false, false, true, false><<<dim3(64, 8, 1), 256, 0, stream>>>(
        esplit, wsplitf, gates_f, nullptr,
        8192, 1024, 320, 640, 640, 1024, 0,
        0L, 0L, 0L, 0L, b_f, nullptr, 1, 0);
    mgemm_k<true, false, false, true, false><<<dim3(64, 8, 1), 256, 0, stream>>>(
        esplit, wsplitb, gates_b, nullptr,
        8192, 1024, 320, 640, 640, 1024, 0,
        0L, 0L, 0L, 0L, b_b, nullptr, 1, 0);

    // 2. biLSTM scan -> rnn [B,S,512] (R7 stamp protocol + off-chain rnn store)
    lstm_reg_k<<<dim3(64, 4), 1024, 0, stream>>>(
        gates_f, gates_b, w_hh_f, w_hh_b, rnn, hbuf, stamp);

    // 3. split conversions for the head
    split_k<<<16384, 256, 0, stream>>>(rnn, rnn_nt16, 8192, 512);
    tsplit_k<<<dim3(8, 4, 32), 256, 0, stream>>>(rnn, rnnT16, 256, 512, 512, 131072, 262144);
    split_k<<<8000, 256, 0, stream>>>(attn_w, attn_ws16, 4000, 512);
    tsplit_k<<<dim3(8, 8, 1), 256, 0, stream>>>(w1, w1t16, 512, 512, 512, 0, 0);
    tsplit_k<<<dim3(4, 8, 1), 256, 0, stream>>>(w2, w2t16, 512, 256, 256, 0, 0);

    // 4. GCN branch on MFMA (runs after lstm in stream order; hbuf region dead)
    split_k<<<4000, 256, 0, stream>>>(label_emb, le16, 4000, 256);
    tsplit_k<<<dim3(8, 4, 1), 256, 0, stream>>>(gcn_w, gw16, 256, 512, 512, 0, 0);
    mgemm_k<false, false, false, true, false><<<dim3(32, 4, 1), 256, 0, stream>>>(
        le16, gw16, gcn_tmp, nullptr,
        4000, 512, 256, 512, 512, 512, 0,
        0L, 0L, 0L, 0L, nullptr, nullptr, 1, 0);
    spmm_k<<<dim3(4000), 256, 0, stream>>>(adj, gcn_tmp, gcn_b, gcn_out);
    split_k<<<8000, 256, 0, stream>>>(gcn_out, go16, 4000, 512);
    tsplit_k<<<dim3(8, 8, 1), 256, 0, stream>>>(w1 + (size_t)512 * 512, w1b16, 512, 512, 512, 0, 0);
    mgemm_k<true, false, false, true, false><<<dim3(32, 4, 1), 256, 0, stream>>>(
        go16, w1b16, contrib, nullptr,
        4000, 512, 512, 1024, 1024, 512, 0,
        0L, 0L, 0L, 0L, b1, nullptr, 1, 0);

    // 5. attention + MLP head (MFMA split-bf16), chunked over batch
    for (int b0 = 0; b0 < 32; b0 += NB) {
        const int nb = (32 - b0 < NB) ? (32 - b0) : NB;
        mgemm_k<false, false, false, true, false><<<dim3(32, 2, nb), 256, 0, stream>>>(
            attn_ws16, rnn_nt16 + (size_t)b0 * 262144, scoresb, nullptr,
            4000, 256, 512, 1024, 1024, 256, 0,
            0L, 262144L, 1024000L, 0L, nullptr, nullptr, 1, 0);
        softmax_split_k<<<dim3(1000, nb), 256, 0, stream>>>(scoresb, tokens, b0);
        mgemm_k<false, false, false, false, true><<<dim3(32, 4, nb), 256, 0, stream>>>(
            (const ushort*)scoresb, rnnT16 + (size_t)b0 * 262144, nullptr, attn16,
            4000, 512, 256, 512, 512, 0, 1024,
            2048000L, 262144L, 0L, 4096000L, nullptr, nullptr, 1, 0);
        mgemm_k<false, true, true, false, true><<<dim3((nb * 4000 + 127) / 128, 4, 1), 256, 0, stream>>>(
            attn16, w1t16, nullptr, x116,
            nb * 4000, 512, 512, 1024, 1024, 0, 1024,
            0L, 0L, 0L, 0L, nullptr, contrib, 4000, 512);
        mgemm_k<true, false, true, true, false><<<dim3((nb * 4000 + 127) / 128, 2, 1), 256, 0, stream>>>(
            x116, w2t16, x2b, nullptr,
            nb * 4000, 256, 512, 1024, 1024, 256, 0,
            0L, 0L, 0L, 0L, b2, nullptr, 1, 0);
        out_k<<<dim3(nb * 1000), 256, 0, stream>>>(x2b, w_out, b_out, outp, b0);
    }
}

// Round 13
// 1754.109 us; speedup vs baseline: 1.2182x; 1.0077x over previous
//
#include <hip/hip_runtime.h>
#include <hip/hip_bf16.h>
#include <math.h>

// Problem constants
// B=32 S=256 E=300 H=256(4H=1024) L=4000 D=256 G=512 V=50000 LIN1=512 LIN2=256, 2H=512

typedef __attribute__((ext_vector_type(8))) short bfrag;   // 8 bf16 (4 VGPRs)
typedef __attribute__((ext_vector_type(4))) float ffrag;   // 4 fp32 acc

__device__ __forceinline__ ushort f2bf(float x) {
    union { float f; unsigned u; } c; c.f = x;
    const unsigned r = c.u + 0x7fffu + ((c.u >> 16) & 1u);
    return (ushort)(r >> 16);
}
__device__ __forceinline__ float bf2f(ushort h) {
    union { unsigned u; float f; } c; c.u = (unsigned)h << 16;
    return c.f;
}

// ---------------------------------------------------------------------------
// Split-bf16 MFMA GEMM: C = A * B^T via 3-term split (hh + hl + lh).
// A: [M][lda] bf16, row = [hi(0..K) | lo(0..K)]; B likewise. Tile 128x128,
// BK=32, 4 waves (2x2 of 64x64). LDS rows padded to 40 bf16 (80B stride).
// Pipeline: next-tile loads issued before the MFMA phase (latency hides).
// R13: grid order n-fastest (blockIdx.x = n-tile) so blocks sharing an
// A-panel are dispatch-adjacent -> panel L2/L3-resident (x1/x2 A re-reads
// were ~1.3GB of far traffic with m-fastest order).
// OUTDOT epilogue: fused final projection (bias+relu, dot with dotw, 16-lane
// butterfly + wn-pair LDS combine, partial per n-block to pd) - removes the
// 262MB x2->out round trip. pdls aliases Ah (dead after main loop).
// ---------------------------------------------------------------------------
template<bool BIAS, bool ADDROW, bool RELU, bool OUTF, bool OUTS, bool OUTDOT>
__global__ __launch_bounds__(256) void mgemm_k(
    const ushort* __restrict__ A, const ushort* __restrict__ B,
    float* __restrict__ Cf, ushort* __restrict__ Cs,
    int M, int N, int K, int lda, int ldb, int ldc, int ldcs,
    long abs_, long bbs_, long cbs_, long csbs_,
    const float* __restrict__ bias,
    const float* __restrict__ addrow, int addmod, int ldadd,
    const float* __restrict__ dotw, float* __restrict__ pd)
{
    const int tid = threadIdx.x;
    const int ln = tid & 63;
    const int wv = tid >> 6;
    const int wm = wv >> 1, wn = wv & 1;
    const int n0 = blockIdx.x * 128;   // n fastest (L2 panel locality)
    const int m0 = blockIdx.y * 128;
    const int z = blockIdx.z;
    A += (size_t)z * abs_;
    B += (size_t)z * bbs_;

    __shared__ ushort Ah[128 * 40], Al[128 * 40], Bh[128 * 40], Bl[128 * 40];

    ffrag acc[4][4];
#pragma unroll
    for (int i = 0; i < 4; ++i)
#pragma unroll
        for (int j = 0; j < 4; ++j) acc[i][j] = ffrag{0.f, 0.f, 0.f, 0.f};

    const int sr = tid >> 1;
    const int sk = (tid & 1) * 16;
    const int am = min(m0 + sr, M - 1);
    const int bn = n0 + sr;
    const int fr = ln & 15;
    const int fk = (ln >> 4) * 8;

    const ushort* arow = A + (size_t)am * lda + sk;
    const ushort* brow = B + (size_t)bn * ldb + sk;

    bfrag ah0, ah1, al0, al1, bh0, bh1, bl0, bl1;
    {
        const ushort* ap = arow;
        const ushort* bp = brow;
        ah0 = *(const bfrag*)ap;       ah1 = *(const bfrag*)(ap + 8);
        al0 = *(const bfrag*)(ap + K); al1 = *(const bfrag*)(ap + K + 8);
        bh0 = *(const bfrag*)bp;       bh1 = *(const bfrag*)(bp + 8);
        bl0 = *(const bfrag*)(bp + K); bl1 = *(const bfrag*)(bp + K + 8);
    }

    for (int k0 = 0; k0 < K; k0 += 32) {
        __syncthreads();   // previous iteration's frag reads complete
        *(bfrag*)&Ah[sr * 40 + sk] = ah0;  *(bfrag*)&Ah[sr * 40 + sk + 8] = ah1;
        *(bfrag*)&Al[sr * 40 + sk] = al0;  *(bfrag*)&Al[sr * 40 + sk + 8] = al1;
        *(bfrag*)&Bh[sr * 40 + sk] = bh0;  *(bfrag*)&Bh[sr * 40 + sk + 8] = bh1;
        *(bfrag*)&Bl[sr * 40 + sk] = bl0;  *(bfrag*)&Bl[sr * 40 + sk + 8] = bl1;
        __syncthreads();   // tile staged
        if (k0 + 32 < K) {  // issue next-tile loads early
            const ushort* ap = arow + k0 + 32;
            const ushort* bp = brow + k0 + 32;
            ah0 = *(const bfrag*)ap;       ah1 = *(const bfrag*)(ap + 8);
            al0 = *(const bfrag*)(ap + K); al1 = *(const bfrag*)(ap + K + 8);
            bh0 = *(const bfrag*)bp;       bh1 = *(const bfrag*)(bp + 8);
            bl0 = *(const bfrag*)(bp + K); bl1 = *(const bfrag*)(bp + K + 8);
        }
        bfrag afh[4], afl[4];
#pragma unroll
        for (int i = 0; i < 4; ++i) {
            const int ar = (wm * 64 + i * 16 + fr) * 40 + fk;
            afh[i] = *(const bfrag*)&Ah[ar];
            afl[i] = *(const bfrag*)&Al[ar];
        }
#pragma unroll
        for (int j = 0; j < 4; ++j) {
            const int br = (wn * 64 + j * 16 + fr) * 40 + fk;
            const bfrag bfh = *(const bfrag*)&Bh[br];
            const bfrag bfl = *(const bfrag*)&Bl[br];
#pragma unroll
            for (int i = 0; i < 4; ++i) {
                acc[i][j] = __builtin_amdgcn_mfma_f32_16x16x32_bf16(afh[i], bfh, acc[i][j], 0, 0, 0);
                acc[i][j] = __builtin_amdgcn_mfma_f32_16x16x32_bf16(afh[i], bfl, acc[i][j], 0, 0, 0);
                acc[i][j] = __builtin_amdgcn_mfma_f32_16x16x32_bf16(afl[i], bfh, acc[i][j], 0, 0, 0);
            }
        }
    }

    if (OUTDOT) {
        // fused projection: rowsum_j relu(acc+bias)*dotw -> pd[nblk][gm]
        float wv4[4], bv4[4];
#pragma unroll
        for (int j = 0; j < 4; ++j) {
            const int gn = n0 + wn * 64 + j * 16 + fr;
            wv4[j] = dotw[gn];
            bv4[j] = BIAS ? bias[gn] : 0.f;
        }
        float rsum[16];
#pragma unroll
        for (int i = 0; i < 4; ++i) {
#pragma unroll
            for (int rg = 0; rg < 4; ++rg) {
                const int gm = m0 + wm * 64 + i * 16 + (ln >> 4) * 4 + rg;
                float p = 0.f;
                if (gm < M) {
#pragma unroll
                    for (int j = 0; j < 4; ++j) {
                        float v = acc[i][j][rg] + bv4[j];
                        if (RELU) v = fmaxf(v, 0.f);
                        p = fmaf(v, wv4[j], p);
                    }
                }
                rsum[i * 4 + rg] = p;
            }
        }
#pragma unroll
        for (int t = 0; t < 16; ++t) {      // butterfly over the 16-lane group
            rsum[t] += __shfl_xor(rsum[t], 1);
            rsum[t] += __shfl_xor(rsum[t], 2);
            rsum[t] += __shfl_xor(rsum[t], 4);
            rsum[t] += __shfl_xor(rsum[t], 8);
        }
        float* pdls = (float*)Ah;           // reuse dead LDS
        __syncthreads();                    // all frag reads done
        if (wn == 0 && fr == 0) {
#pragma unroll
            for (int i = 0; i < 4; ++i)
#pragma unroll
                for (int rg = 0; rg < 4; ++rg)
                    pdls[wm * 64 + i * 16 + (ln >> 4) * 4 + rg] = rsum[i * 4 + rg];
        }
        __syncthreads();
        if (wn == 1 && fr == 0) {
#pragma unroll
            for (int i = 0; i < 4; ++i)
#pragma unroll
                for (int rg = 0; rg < 4; ++rg) {
                    const int lr = wm * 64 + i * 16 + (ln >> 4) * 4 + rg;
                    const int gm = m0 + lr;
                    if (gm < M) pd[(size_t)blockIdx.x * M + gm] = pdls[lr] + rsum[i * 4 + rg];
                }
        }
        return;
    }

#pragma unroll
    for (int i = 0; i < 4; ++i) {
#pragma unroll
        for (int rg = 0; rg < 4; ++rg) {
            const int gm = m0 + wm * 64 + i * 16 + (ln >> 4) * 4 + rg;
            if (gm >= M) continue;
            const float* addp = ADDROW ? (addrow + (size_t)(gm % addmod) * ldadd) : nullptr;
#pragma unroll
            for (int j = 0; j < 4; ++j) {
                const int gn = n0 + wn * 64 + j * 16 + fr;
                float v = acc[i][j][rg];
                if (BIAS) v += bias[gn];
                if (ADDROW) v += addp[gn];
                if (RELU) v = fmaxf(v, 0.f);
                if (OUTF) Cf[(size_t)z * cbs_ + (size_t)gm * ldc + gn] = v;
                if (OUTS) {
                    const ushort h = f2bf(v);
                    const ushort l = f2bf(v - bf2f(h));
                    ushort* cp = Cs + (size_t)z * csbs_ + (size_t)gm * ldcs;
                    cp[gn] = h;
                    cp[N + gn] = l;
                }
            }
        }
    }
}

// ---------------------------------------------------------------------------
// Final sum of the two OUTDOT partials (fixed order -> deterministic).
// ---------------------------------------------------------------------------
__global__ void outsum_k(const float* __restrict__ pd, const float* __restrict__ b_out,
                         float* __restrict__ outp, int M, int b0)
{
    const int r = blockIdx.x * 256 + threadIdx.x;
    if (r >= M) return;
    const int bb = r / 4000, l = r - bb * 4000;
    outp[(size_t)(b0 + bb) * 4000 + l] = (pd[r] + pd[(size_t)M + r]) + b_out[0];
}

// ---------------------------------------------------------------------------
// Gather(optional) + split + zero-pad: row r of src (K cols) -> [r][2*Kpad]
// ---------------------------------------------------------------------------
__global__ void gsplit_k(const float* __restrict__ src, const int* __restrict__ tok,
                         ushort* __restrict__ outp, int K, int Kpad)
{
    const int r = blockIdx.x;
    const float* s = src + (size_t)(tok ? tok[r] : r) * K;
    ushort* o = outp + (size_t)r * 2 * Kpad;
    for (int k = threadIdx.x; k < Kpad; k += blockDim.x) {
        const float x = (k < K) ? s[k] : 0.f;
        const ushort h = f2bf(x);
        const ushort l = f2bf(x - bf2f(h));
        o[k] = h;
        o[Kpad + k] = l;
    }
}

// ---------------------------------------------------------------------------
// fp32 [rows][K] -> split bf16 [rows][2K] (hi | lo)
// ---------------------------------------------------------------------------
__global__ void split_k(const float* __restrict__ in, ushort* __restrict__ outp,
                        int rows, int K)
{
    const int i = blockIdx.x * 256 + threadIdx.x;
    if (i >= rows * K) return;
    const int r = i / K, k = i - r * K;
    const float x = in[i];
    const ushort h = f2bf(x);
    const ushort l = f2bf(x - bf2f(h));
    ushort* o = outp + (size_t)r * 2 * K;
    o[k] = h;
    o[K + k] = l;
}

// ---------------------------------------------------------------------------
// fp32 [R][C] -> split-transposed bf16 [C][2R]
// ---------------------------------------------------------------------------
__global__ __launch_bounds__(256) void tsplit_k(
    const float* __restrict__ in, ushort* __restrict__ outp,
    int R, int C, int ldin, long ibs, long obs)
{
    __shared__ float t[64][65];
    const int c0 = blockIdx.x * 64, r0 = blockIdx.y * 64;
    in   += (size_t)blockIdx.z * ibs;
    outp += (size_t)blockIdx.z * obs;
    const int tx = threadIdx.x & 15, ty = threadIdx.x >> 4;
#pragma unroll
    for (int i = 0; i < 4; ++i) {
        const int r = ty * 4 + i;
        const float4 v = *(const float4*)&in[(size_t)(r0 + r) * ldin + c0 + tx * 4];
        t[tx * 4 + 0][r] = v.x;
        t[tx * 4 + 1][r] = v.y;
        t[tx * 4 + 2][r] = v.z;
        t[tx * 4 + 3][r] = v.w;
    }
    __syncthreads();
    const int R2 = 2 * R;
#pragma unroll
    for (int i = 0; i < 4; ++i) {
        const int c = ty * 4 + i;
        ushort h[4], l[4];
#pragma unroll
        for (int k2 = 0; k2 < 4; ++k2) {
            const float x = t[c][tx * 4 + k2];
            h[k2] = f2bf(x);
            l[k2] = f2bf(x - bf2f(h[k2]));
        }
        uint2 hw, lw;
        hw.x = (unsigned)h[0] | ((unsigned)h[1] << 16);
        hw.y = (unsigned)h[2] | ((unsigned)h[3] << 16);
        lw.x = (unsigned)l[0] | ((unsigned)l[1] << 16);
        lw.y = (unsigned)l[2] | ((unsigned)l[3] << 16);
        *(uint2*)&outp[(size_t)(c0 + c) * R2 + r0 + tx * 4] = hw;
        *(uint2*)&outp[(size_t)(c0 + c) * R2 + R + r0 + tx * 4] = lw;
    }
}

// ---------------------------------------------------------------------------
// Register-resident biLSTM scan: R7/R9 stamp protocol, byte-for-byte the
// measured best (622us). [R8/R11/R12 lessons: distributed spins, per-wave
// sub-stamps, and rnn-store reordering all regressed or were neutral —
// single-poller + B3 drain + rnn-before-B3 is the floor of this family.]
// Co-residency: 256 blocks <= 256 CUs (1 block/CU) => no deadlock.
// ---------------------------------------------------------------------------
__global__ __launch_bounds__(1024) void lstm_reg_k(
    const float* __restrict__ gxf, const float* __restrict__ gxb,
    const float* __restrict__ whf, const float* __restrict__ whb,
    float* __restrict__ rnn, float* hbuf, int* stamp)
{
    const int p = blockIdx.x;          // pair: batch b=p>>1, dir=p&1
    const int q = blockIdx.y;          // quarter (owns units [64q,64q+64))
    const int b = p >> 1, dir = p & 1;
    const float* xg = dir ? gxb : gxf;
    const float* W  = dir ? whb : whf;
    const int tid = threadIdx.x;
    const int wv = tid >> 6, lane = tid & 63;
    const int ul = lane >> 4;           // unit-local 0..3
    const int ks = (lane >> 2) & 3;     // 64-float k-slice
    const int gt = lane & 3;            // gate 0..3 (i,f,g,o)
    const int u  = wv * 4 + ul;         // block unit 0..63
    const int grow = gt * 256 + q * 64 + u;

    float4 w[16];
    {
        const float4* wp = (const float4*)(W + (size_t)grow * 256 + ks * 64);
#pragma unroll
        for (int i = 0; i < 16; ++i) w[i] = wp[i];
    }

    __shared__ float h_lds[4 * 68];
    __shared__ float xg_lds[320];       // [u*5 + gt], stride 5 = conflict-free

    float* hb0 = hbuf + (size_t)p * 256;            // parity 0
    float* hb1 = hbuf + (size_t)(64 + p) * 256;     // parity 1
    int* sp = stamp + p * 16;

    const size_t xgb = (size_t)b * 256;
    const int g2 = (tid >> 6) * 256 + q * 64 + (tid & 63);  // staging map (tid<256)
    float c = 0.f;                                   // redundant in all lanes
    float xg_cur = 0.f;
    if (tid < 256) xg_cur = xg[(xgb + (dir ? 255 : 0)) * 1024 + g2];

    for (int st = 0; st < 256; ++st) {
        const int ts = dir ? 255 - st : st;
        if (st > 0 && tid == 0) {
            while (true) {
                int s0 = __hip_atomic_load(&sp[0], __ATOMIC_RELAXED, __HIP_MEMORY_SCOPE_AGENT);
                int s1 = __hip_atomic_load(&sp[1], __ATOMIC_RELAXED, __HIP_MEMORY_SCOPE_AGENT);
                int s2 = __hip_atomic_load(&sp[2], __ATOMIC_RELAXED, __HIP_MEMORY_SCOPE_AGENT);
                int s3 = __hip_atomic_load(&sp[3], __ATOMIC_RELAXED, __HIP_MEMORY_SCOPE_AGENT);
                if (min(min(s0, s1), min(s2, s3)) >= st) break;
            }
        }
        __syncthreads();   // B1: partners' h[st-1] published (via atomics)
        if (tid < 256) {
            float hv = 0.f;
            if (st > 0) {
                const float* src = (st & 1) ? hb0 : hb1;   // parity (st-1)&1
                hv = __hip_atomic_load(&src[tid], __ATOMIC_RELAXED, __HIP_MEMORY_SCOPE_AGENT);
            }
            h_lds[(tid >> 6) * 68 + (tid & 63)] = hv;
            xg_lds[(tid & 63) * 5 + (tid >> 6)] = xg_cur;  // [u][gt] stride-5
        }
        __syncthreads();   // B2: h_lds/xg_lds ready
        float acc = 0.f;
        {
            const float4* hp = (const float4*)&h_lds[ks * 68];
#pragma unroll
            for (int i = 0; i < 16; ++i) {
                const float4 hv = hp[i];
                acc = fmaf(w[i].x, hv.x, acc);
                acc = fmaf(w[i].y, hv.y, acc);
                acc = fmaf(w[i].z, hv.z, acc);
                acc = fmaf(w[i].w, hv.w, acc);
            }
        }
        acc += __shfl_xor(acc, 4);      // reduce over ks (bits 2-3)
        acc += __shfl_xor(acc, 8);
        const float g = acc + xg_lds[u * 5 + gt];
        // gather quartet gates via xor-shfls; all lanes act redundantly
        const float t1 = __shfl_xor(g, 1);
        const float t2 = __shfl_xor(g, 2);
        const float t3 = __shfl_xor(t1, 2);
        const float g0 = (gt == 0) ? g : (gt == 1) ? t1 : (gt == 2) ? t2 : t3;
        const float g1 = (gt == 1) ? g : (gt == 0) ? t1 : (gt == 3) ? t2 : t3;
        const float g2v = (gt == 2) ? g : (gt == 3) ? t1 : (gt == 0) ? t2 : t3;
        const float g3v = (gt == 3) ? g : (gt == 2) ? t1 : (gt == 1) ? t2 : t3;
        const float si = 1.f / (1.f + __expf(-g0));
        const float sf = 1.f / (1.f + __expf(-g1));
        const float so = 1.f / (1.f + __expf(-g3v));
        const float tg = 1.f - 2.f / (__expf(2.f * g2v) + 1.f);
        c = sf * c + si * tg;
        const float tc = 1.f - 2.f / (__expf(2.f * c) + 1.f);
        const float hn = so * tc;
        if ((lane & 15) == 0) {          // ks==0 && gt==0: one lane per unit
            float* dst = (st & 1) ? hb1 : hb0;       // parity st&1
            __hip_atomic_store(&dst[q * 64 + u], hn, __ATOMIC_RELAXED, __HIP_MEMORY_SCOPE_AGENT);
            rnn[(xgb + ts) * 512 + (size_t)dir * 256 + q * 64 + u] = hn;
        }
        __syncthreads();   // B3: every wave drains vmcnt(0) -> all h stores acked
        if (tid == 0) {
            __hip_atomic_store(&sp[q], st + 1, __ATOMIC_RELAXED, __HIP_MEMORY_SCOPE_AGENT);
        }
        // prefetch next step's xg (off critical path)
        if (tid < 256 && st < 255) {
            const int tsn = dir ? 254 - st : st + 1;
            xg_cur = xg[(xgb + tsn) * 1024 + g2];
        }
    }
}

__global__ void init_cnt_k(int* stamp) {
    const int i = blockIdx.x * blockDim.x + threadIdx.x;
    if (i < 1024) stamp[i] = 0;
}

// ---------------------------------------------------------------------------
// Masked softmax over s (256); writes split-bf16 probs in place.
// ---------------------------------------------------------------------------
__global__ __launch_bounds__(256) void softmax_split_k(
    float* __restrict__ sc, const int* __restrict__ tokens, int b0)
{
    const int bb = blockIdx.y;
    const int l  = blockIdx.x * 4 + (threadIdx.x >> 6);
    const int lane = threadIdx.x & 63;
    float* row = sc + ((size_t)bb * 4000 + l) * 256;
    const int* tk = tokens + (size_t)(b0 + bb) * 256;
    float4 v = *(const float4*)&row[lane * 4];
    const int4 tv = *(const int4*)&tk[lane * 4];
    if (tv.x == 0) v.x = -1e9f;
    if (tv.y == 0) v.y = -1e9f;
    if (tv.z == 0) v.z = -1e9f;
    if (tv.w == 0) v.w = -1e9f;
    float mx = fmaxf(fmaxf(v.x, v.y), fmaxf(v.z, v.w));
    for (int o = 32; o > 0; o >>= 1) mx = fmaxf(mx, __shfl_xor(mx, o));
    v.x = __expf(v.x - mx); v.y = __expf(v.y - mx);
    v.z = __expf(v.z - mx); v.w = __expf(v.w - mx);
    float s = v.x + v.y + v.z + v.w;
    for (int o = 32; o > 0; o >>= 1) s += __shfl_xor(s, o);
    const float inv = 1.f / s;
    const float p0 = v.x * inv, p1 = v.y * inv, p2 = v.z * inv, p3 = v.w * inv;
    const ushort h0 = f2bf(p0), h1 = f2bf(p1), h2 = f2bf(p2), h3 = f2bf(p3);
    const ushort l0 = f2bf(p0 - bf2f(h0)), l1 = f2bf(p1 - bf2f(h1));
    const ushort l2 = f2bf(p2 - bf2f(h2)), l3 = f2bf(p3 - bf2f(h3));
    ushort* orow = (ushort*)row;
    uint2 hw, lw;
    hw.x = (unsigned)h0 | ((unsigned)h1 << 16);
    hw.y = (unsigned)h2 | ((unsigned)h3 << 16);
    lw.x = (unsigned)l0 | ((unsigned)l1 << 16);
    lw.y = (unsigned)l2 | ((unsigned)l3 << 16);
    *(uint2*)&orow[lane * 4] = hw;
    *(uint2*)&orow[256 + lane * 4] = lw;
}

// ---------------------------------------------------------------------------
// Sparse GCN aggregation.
// ---------------------------------------------------------------------------
__global__ __launch_bounds__(256) void spmm_k(
    const float* __restrict__ adj, const float* __restrict__ tmp,
    const float* __restrict__ bias, float* __restrict__ outp)
{
    const int l = blockIdx.x;
    __shared__ int   idxs[4][256];
    __shared__ float vals[4][256];
    __shared__ int   cnts[4];
    const int t = threadIdx.x;
    const int w = t >> 6, lane = t & 63;
    const float* arow = adj + (size_t)l * 4000;
    int cnt = 0;
    for (int r = 0; r < 16; ++r) {
        const int o = r * 64 + lane;
        const int j = w * 1000 + o;
        const float a = (o < 1000) ? arow[j] : 0.f;
        const unsigned long long mk = __ballot(a != 0.f);
        if (a != 0.f) {
            const int pos = cnt + __popcll(mk & ((1ull << lane) - 1ull));
            if (pos < 256) { idxs[w][pos] = j; vals[w][pos] = a; }
        }
        cnt += __popcll(mk);
    }
    if (lane == 0) cnts[w] = min(cnt, 256);
    __syncthreads();
    const int c0 = t * 2;
    float a0 = 0.f, a1 = 0.f;
    for (int ww = 0; ww < 4; ++ww) {
        const int n = cnts[ww];
        for (int e = 0; e < n; ++e) {
            const float a = vals[ww][e];
            const float2 tv = *(const float2*)&tmp[(size_t)idxs[ww][e] * 512 + c0];
            a0 = fmaf(a, tv.x, a0);
            a1 = fmaf(a, tv.y, a1);
        }
    }
    float2 res;
    res.x = fmaxf(a0 + bias[c0], 0.f);
    res.y = fmaxf(a1 + bias[c0 + 1], 0.f);
    *(float2*)&outp[(size_t)l * 512 + c0] = res;
}

// ---------------------------------------------------------------------------
extern "C" void kernel_launch(void* const* d_in, const int* in_sizes, int n_in,
                              void* d_out, int out_size, void* d_ws, size_t ws_size,
                              hipStream_t stream)
{
    const int*   tokens    = (const int*)  d_in[0];
    const float* emb       = (const float*)d_in[1];
    const float* w_ih_f    = (const float*)d_in[2];
    const float* w_hh_f    = (const float*)d_in[3];
    const float* b_f       = (const float*)d_in[4];
    const float* w_ih_b    = (const float*)d_in[5];
    const float* w_hh_b    = (const float*)d_in[6];
    const float* b_b       = (const float*)d_in[7];
    const float* attn_w    = (const float*)d_in[8];
    const float* label_emb = (const float*)d_in[9];
    const float* adj       = (const float*)d_in[10];
    const float* gcn_w     = (const float*)d_in[11];
    const float* gcn_b     = (const float*)d_in[12];
    const float* w1        = (const float*)d_in[13];
    const float* b1        = (const float*)d_in[14];
    const float* w2        = (const float*)d_in[15];
    const float* b2        = (const float*)d_in[16];
    const float* w_out     = (const float*)d_in[17];
    const float* b_out     = (const float*)d_in[18];
    float* outp = (float*)d_out;
    float* wsf  = (float*)d_ws;

    // ---- workspace layout (float offsets) ----
    const size_t off_gf  = 0;          // gates_f 8.39M
    const size_t off_gb  = 8388608;    // gates_b 8.39M
    const size_t off_rnn = 16777216;   // rnn fp32 4.19M
    const size_t off_tmp = 20971520;   // gcn_tmp 2.05M (lstm hbuf/stamp overlay)
    const size_t off_go  = 23019520;   // gcn_out 2.05M
    const size_t off_ctr = 25067520;   // contrib 2.05M
    const size_t base_end = 27115520;
    const size_t S_sz = 10829824;
    const size_t have = ws_size / 4;
    int NB = 1; size_t offS = off_gf, offC = off_gf + S_sz;
    {
        const int tiers[6] = {32, 16, 8, 4, 2, 0};
        bool found = false;
        for (int t = 0; tiers[t]; ++t) {
            if (have >= base_end + S_sz + (size_t)tiers[t] * 5120000) {
                NB = tiers[t]; offS = base_end; offC = base_end + S_sz; found = true; break;
            }
        }
        if (!found && have >= base_end + S_sz) { NB = 2; offS = base_end; offC = off_gf; }
    }

    float* gates_f = wsf + off_gf;
    float* gates_b = wsf + off_gb;
    float* rnn     = wsf + off_rnn;
    float* gcn_tmp = wsf + off_tmp;
    float* gcn_out = wsf + off_go;
    float* contrib = wsf + off_ctr;
    float* hbuf    = wsf + off_tmp;                  // [2][64][256] overlay
    int*   stamp   = (int*)(wsf + off_tmp + 32768);  // [64][16] overlay

    // pre-lstm split staging (dead before its host region is reused)
    const size_t off_esp = (offS == off_gf) ? off_rnn : offS;
    ushort* esplit  = (ushort*)(wsf + off_esp);
    ushort* wsplitf = esplit + (size_t)8192 * 640;
    ushort* wsplitb = wsplitf + (size_t)1024 * 640;

    ushort* attn_ws16 = (ushort*)(wsf + offS);                // [4000][1024]
    ushort* w1t16     = (ushort*)(wsf + offS + 2048000);      // [512][1024]
    ushort* w2t16     = (ushort*)(wsf + offS + 2310144);      // [256][1024]
    ushort* rnn_nt16  = (ushort*)(wsf + offS + 2441216);      // [32][256][1024]
    ushort* rnnT16    = (ushort*)(wsf + offS + 6635520);      // [32][512][512]

    float*  scoresb = wsf + offC;
    ushort* attn16  = (ushort*)(wsf + offC + (size_t)NB * 1024000);
    ushort* x116    = (ushort*)(wsf + offC + (size_t)NB * 1024000 + (size_t)NB * 2048000);
    float*  pd      = scoresb;   // [2][NB*4000] partials (probs dead by x2)

    // GCN split staging, overlays the chunk region (dead before head loop)
    ushort* le16   = (ushort*)(wsf + offC);                   // [4000][512]
    ushort* gw16   = le16 + (size_t)4000 * 512;               // [512][512]
    ushort* go16   = gw16 + (size_t)512 * 512;                // [4000][1024]
    ushort* w1b16  = go16 + (size_t)4000 * 1024;              // [512][1024]

    // 0. zero lstm stamps (graph-replay safe)
    init_cnt_k<<<4, 256, 0, stream>>>(stamp);

    // 1. input projections on MFMA
    gsplit_k<<<8192, 256, 0, stream>>>(emb, tokens, esplit, 300, 320);
    gsplit_k<<<1024, 256, 0, stream>>>(w_ih_f, nullptr, wsplitf, 300, 320);
    gsplit_k<<<1024, 256, 0, stream>>>(w_ih_b, nullptr, wsplitb, 300, 320);
    mgemm_k<true, false, false, true, false, false><<<dim3(8, 64, 1), 256, 0, stream>>>(
        esplit, wsplitf, gates_f, nullptr,
        8192, 1024, 320, 640, 640, 1024, 0,
        0L, 0L, 0L, 0L, b_f, nullptr, 1, 0, nullptr, nullptr);
    mgemm_k<true, false, false, true, false, false><<<dim3(8, 64, 1), 256, 0, stream>>>(
        esplit, wsplitb, gates_b, nullptr,
        8192, 1024, 320, 640, 640, 1024, 0,
        0L, 0L, 0L, 0L, b_b, nullptr, 1, 0, nullptr, nullptr);

    // 2. biLSTM scan -> rnn [B,S,512] (R9 protocol, measured best)
    lstm_reg_k<<<dim3(64, 4), 1024, 0, stream>>>(
        gates_f, gates_b, w_hh_f, w_hh_b, rnn, hbuf, stamp);

    // 3. split conversions for the head
    split_k<<<16384, 256, 0, stream>>>(rnn, rnn_nt16, 8192, 512);
    tsplit_k<<<dim3(8, 4, 32), 256, 0, stream>>>(rnn, rnnT16, 256, 512, 512, 131072, 262144);
    split_k<<<8000, 256, 0, stream>>>(attn_w, attn_ws16, 4000, 512);
    tsplit_k<<<dim3(8, 8, 1), 256, 0, stream>>>(w1, w1t16, 512, 512, 512, 0, 0);
    tsplit_k<<<dim3(4, 8, 1), 256, 0, stream>>>(w2, w2t16, 512, 256, 256, 0, 0);

    // 4. GCN branch on MFMA
    split_k<<<4000, 256, 0, stream>>>(label_emb, le16, 4000, 256);
    tsplit_k<<<dim3(8, 4, 1), 256, 0, stream>>>(gcn_w, gw16, 256, 512, 512, 0, 0);
    mgemm_k<false, false, false, true, false, false><<<dim3(4, 32, 1), 256, 0, stream>>>(
        le16, gw16, gcn_tmp, nullptr,
        4000, 512, 256, 512, 512, 512, 0,
        0L, 0L, 0L, 0L, nullptr, nullptr, 1, 0, nullptr, nullptr);
    spmm_k<<<dim3(4000), 256, 0, stream>>>(adj, gcn_tmp, gcn_b, gcn_out);
    split_k<<<8000, 256, 0, stream>>>(gcn_out, go16, 4000, 512);
    tsplit_k<<<dim3(8, 8, 1), 256, 0, stream>>>(w1 + (size_t)512 * 512, w1b16, 512, 512, 512, 0, 0);
    mgemm_k<true, false, false, true, false, false><<<dim3(4, 32, 1), 256, 0, stream>>>(
        go16, w1b16, contrib, nullptr,
        4000, 512, 512, 1024, 1024, 512, 0,
        0L, 0L, 0L, 0L, b1, nullptr, 1, 0, nullptr, nullptr);

    // 5. attention + MLP head (MFMA split-bf16), chunked over batch
    for (int b0 = 0; b0 < 32; b0 += NB) {
        const int nb = (32 - b0 < NB) ? (32 - b0) : NB;
        mgemm_k<false, false, false, true, false, false><<<dim3(2, 32, nb), 256, 0, stream>>>(
            attn_ws16, rnn_nt16 + (size_t)b0 * 262144, scoresb, nullptr,
            4000, 256, 512, 1024, 1024, 256, 0,
            0L, 262144L, 1024000L, 0L, nullptr, nullptr, 1, 0, nullptr, nullptr);
        softmax_split_k<<<dim3(1000, nb), 256, 0, stream>>>(scoresb, tokens, b0);
        mgemm_k<false, false, false, false, true, false><<<dim3(4, 32, nb), 256, 0, stream>>>(
            (const ushort*)scoresb, rnnT16 + (size_t)b0 * 262144, nullptr, attn16,
            4000, 512, 256, 512, 512, 0, 1024,
            2048000L, 262144L, 0L, 4096000L, nullptr, nullptr, 1, 0, nullptr, nullptr);
        mgemm_k<false, true, true, false, true, false><<<dim3(4, (nb * 4000 + 127) / 128, 1), 256, 0, stream>>>(
            attn16, w1t16, nullptr, x116,
            nb * 4000, 512, 512, 1024, 1024, 0, 1024,
            0L, 0L, 0L, 0L, nullptr, contrib, 4000, 512, nullptr, nullptr);
        // x2 fused with final projection: partial dots per n-block -> pd
        mgemm_k<true, false, true, false, false, true><<<dim3(2, (nb * 4000 + 127) / 128, 1), 256, 0, stream>>>(
            x116, w2t16, nullptr, nullptr,
            nb * 4000, 256, 512, 1024, 1024, 0, 0,
            0L, 0L, 0L, 0L, b2, nullptr, 1, 0, w_out, pd);
        outsum_k<<<(nb * 4000 + 255) / 256, 256, 0, stream>>>(pd, b_out, outp, nb * 4000, b0);
    }
}